// Round 1
// baseline (1361.655 us; speedup 1.0000x reference)
//
#include <hip/hip_runtime.h>
#include <stdint.h>

// GraphSAGE fused layer, MI355X (gfx950). All tensors fp32.
// N=16384, D=64. adj = binary fp32 mask (1.074 GB) -> must stream once.
//
// R5 theory: prior one-wave-per-row scan ran at 3.4 TB/s while the harness's
// own fillBufferAligned sustains 6.2-6.3 TB/s on the same-size buffer. The
// difference is pattern structure: 4096 narrow per-wave streams (8 KB in
// flight inside 64 KB-aligned rows) vs one device-contiguous front. Stage
// stagger inside the row (R4) didn't help => the stream-per-wave structure is
// the limiter. Fix: two-phase. Phase 1 reads adj with the fill-isomorphic
// grid-stride dwordx4 pattern and scatters nonzero columns into per-row lists
// in the workspace (global atomics: ~524K total, trivial). Phase 2 is the old
// kernel's tail: gather X (L2/L3-hot), GEMV with W, ReLU, row L2-norm.
// Old single-kernel path kept as fallback if ws_size is too small.

#define NROWS   16384
#define DDIM    64
#define MAXNNZ  256        // fallback-kernel list capacity
#define MAXN    128        // ws list width; deg ~ Binom mean 32 sigma 5.7
#define NBLOCKS 4096
#define SCAN_TPB    256
#define SCAN_BLOCKS 2048   // 8 blocks/CU, max-occupancy tiny kernel

typedef uint32_t u32x4 __attribute__((ext_vector_type(4)));

// ---------------------------------------------------------------------------
// Phase 1: device-contiguous scan of adj (fill-like address pattern).
// ---------------------------------------------------------------------------
__device__ __forceinline__ void proc_vec(u32x4 v, int vi,
                                         int* __restrict__ cnt,
                                         int* __restrict__ list) {
    if (v.x | v.y | v.z | v.w) {              // fp32 0.0f == all-zero bits
        const uint32_t wd[4] = { v.x, v.y, v.z, v.w };
#pragma unroll
        for (int j = 0; j < 4; ++j) {
            if (wd[j]) {
                const int e = vi * 4 + j;     // linear element index < 2^28
                const int r = e >> 14;        // row
                const int c = e & (NROWS - 1);
                const int p = atomicAdd(&cnt[r], 1);
                if (p < MAXN) list[(size_t)r * MAXN + p] = c;
            }
        }
    }
}

__global__ __launch_bounds__(SCAN_TPB, 4) void adj_scan(
    const float* __restrict__ adj,
    int* __restrict__ cnt,      // (NROWS) zeroed before launch
    int* __restrict__ list)     // (NROWS, MAXN)
{
    const u32x4* p = reinterpret_cast<const u32x4*>(adj);
    const int stride = SCAN_BLOCKS * SCAN_TPB;           // 524,288 vecs
    int i = blockIdx.x * SCAN_TPB + threadIdx.x;
    // nvec = NROWS*NROWS/4 = 67,108,864 = 32 iters * 4 * stride. Exact.
    // 4 strided loads in flight per wave (4 KB MLP) before processing.
    for (int it = 0; it < 32; ++it) {
        const int i0 = i;
        const int i1 = i + stride;
        const int i2 = i + 2 * stride;
        const int i3 = i + 3 * stride;
        const u32x4 v0 = __builtin_nontemporal_load(&p[i0]);
        const u32x4 v1 = __builtin_nontemporal_load(&p[i1]);
        const u32x4 v2 = __builtin_nontemporal_load(&p[i2]);
        const u32x4 v3 = __builtin_nontemporal_load(&p[i3]);
        proc_vec(v0, i0, cnt, list);
        proc_vec(v1, i1, cnt, list);
        proc_vec(v2, i2, cnt, list);
        proc_vec(v3, i3, cnt, list);
        i += 4 * stride;
    }
}

// ---------------------------------------------------------------------------
// Phase 2: per-row gather + GEMV + ReLU + L2-normalize. One wave per row.
// ---------------------------------------------------------------------------
__global__ __launch_bounds__(256, 4) void sage_agg(
    const float* __restrict__ X,     // (N, 64)
    const int*   __restrict__ cnt,   // (N)
    const int*   __restrict__ list,  // (N, MAXN)
    const float* __restrict__ W,     // (128, 64) row-major, L2-hot (32 KB)
    const float* __restrict__ bias,  // (64,)
    float* __restrict__ out)         // (N, 64)
{
    __shared__ float scat[4][2 * DDIM];  // per-wave [x_i | h_neigh]

    const int tid  = threadIdx.x;
    const int lane = tid & 63;
    const int w    = tid >> 6;
    const int row  = blockIdx.x * 4 + w;

    const float bv = bias[lane];

    const int nnz = cnt[row];
    const int cn  = (nnz < MAXN) ? nnz : MAXN;
    const int* lp = list + (size_t)row * MAXN;

    // Gather-accumulate neighbor X rows (256 B coalesced reads, cache-hot).
    float acc = 0.0f;
    int k = 0;
    for (; k + 4 <= cn; k += 4) {
        const int j0 = lp[k], j1 = lp[k + 1], j2 = lp[k + 2], j3 = lp[k + 3];
        const float a0 = X[(size_t)j0 * DDIM + lane];
        const float a1 = X[(size_t)j1 * DDIM + lane];
        const float a2 = X[(size_t)j2 * DDIM + lane];
        const float a3 = X[(size_t)j3 * DDIM + lane];
        acc += (a0 + a1) + (a2 + a3);
    }
    for (; k < cn; ++k) acc += X[(size_t)lp[k] * DDIM + lane];

    const float xi = X[(size_t)row * DDIM + lane];
    const float h  = (acc + xi) / ((float)nnz + 1.0f);   // deg = rowsum+1 >= 1
    scat[w][lane]        = xi;
    scat[w][DDIM + lane] = h;
    __builtin_amdgcn_wave_barrier();

    // GEMV: z[d] = b[d] + sum_k cat[k] * W[k][d]; W is L1/L2-hot.
    float z0 = bv, z1 = 0.0f, z2 = 0.0f, z3 = 0.0f;
#pragma unroll 8
    for (int kk = 0; kk < 2 * DDIM; kk += 4) {
        z0 = fmaf(scat[w][kk + 0], W[(kk + 0) * DDIM + lane], z0);
        z1 = fmaf(scat[w][kk + 1], W[(kk + 1) * DDIM + lane], z1);
        z2 = fmaf(scat[w][kk + 2], W[(kk + 2) * DDIM + lane], z2);
        z3 = fmaf(scat[w][kk + 3], W[(kk + 3) * DDIM + lane], z3);
    }
    float z = (z0 + z1) + (z2 + z3);
    z = fmaxf(z, 0.0f);

    // Row L2-norm over the 64 lanes, normalize, store.
    float s2 = z * z;
#pragma unroll
    for (int off = 32; off >= 1; off >>= 1) s2 += __shfl_xor(s2, off);
    const float inv = 1.0f / fmaxf(sqrtf(s2), 1e-12f);
    out[(size_t)row * DDIM + lane] = z * inv;
}

// ---------------------------------------------------------------------------
// Fallback: previous best single-kernel path (used only if ws too small).
// ---------------------------------------------------------------------------
__global__ __launch_bounds__(256, 4) void sage_fused(
    const float* __restrict__ X,
    const float* __restrict__ adj,
    const float* __restrict__ W,
    const float* __restrict__ bias,
    float* __restrict__ out)
{
    __shared__ int   slist[4][MAXNNZ];
    __shared__ int   scnt[4];
    __shared__ float scat[4][2 * DDIM];

    const int tid  = threadIdx.x;
    const int lane = tid & 63;
    const int w    = tid >> 6;
    const int row  = blockIdx.x * 4 + w;

    const float bv = bias[lane];

    if (lane == 0) scnt[w] = 0;
    __builtin_amdgcn_wave_barrier();

    const int start = (row * 7 + (row >> 4)) & 15;
    const u32x4* rowp = reinterpret_cast<const u32x4*>(adj + (size_t)row * NROWS);

    u32x4 buf[2][4];
    {
        const int ss0 = start;
        const int ss1 = (start + 1) & 15;
#pragma unroll
        for (int q = 0; q < 4; ++q)
            buf[0][q] = __builtin_nontemporal_load(&rowp[ss0 * 256 + q * 64 + lane]);
#pragma unroll
        for (int q = 0; q < 4; ++q)
            buf[1][q] = __builtin_nontemporal_load(&rowp[ss1 * 256 + q * 64 + lane]);
    }

#pragma unroll 2
    for (int s = 0; s < 16; ++s) {
        const int cur = s & 1;
        const int ss  = (s + start) & 15;
#pragma unroll
        for (int q = 0; q < 4; ++q) {
            const u32x4 vv = buf[cur][q];
            if (vv.x | vv.y | vv.z | vv.w) {
                const int base = (ss * 256 + q * 64 + lane) * 4;
                const uint32_t w4[4] = { vv.x, vv.y, vv.z, vv.w };
#pragma unroll
                for (int j = 0; j < 4; ++j) {
                    if (w4[j]) {
                        const int p = atomicAdd(&scnt[w], 1);
                        if (p < MAXNNZ) slist[w][p] = base + j;
                    }
                }
            }
        }
        if (s < 14) {
            const int ssn = (s + 2 + start) & 15;
#pragma unroll
            for (int q = 0; q < 4; ++q)
                buf[cur][q] = __builtin_nontemporal_load(&rowp[ssn * 256 + q * 64 + lane]);
        }
    }
    __builtin_amdgcn_wave_barrier();

    const int nnz = scnt[w];
    const int cn  = (nnz < MAXNNZ) ? nnz : MAXNNZ;

    float acc = 0.0f;
    int k = 0;
    for (; k + 4 <= cn; k += 4) {
        const int j0 = slist[w][k], j1 = slist[w][k + 1];
        const int j2 = slist[w][k + 2], j3 = slist[w][k + 3];
        const float a0 = X[(size_t)j0 * DDIM + lane];
        const float a1 = X[(size_t)j1 * DDIM + lane];
        const float a2 = X[(size_t)j2 * DDIM + lane];
        const float a3 = X[(size_t)j3 * DDIM + lane];
        acc += (a0 + a1) + (a2 + a3);
    }
    for (; k < cn; ++k) acc += X[(size_t)slist[w][k] * DDIM + lane];

    const float xi = X[(size_t)row * DDIM + lane];
    const float h  = (acc + xi) / ((float)nnz + 1.0f);
    scat[w][lane]        = xi;
    scat[w][DDIM + lane] = h;
    __builtin_amdgcn_wave_barrier();

    float z0 = bv, z1 = 0.0f, z2 = 0.0f, z3 = 0.0f;
#pragma unroll 8
    for (int kk = 0; kk < 2 * DDIM; kk += 4) {
        z0 = fmaf(scat[w][kk + 0], W[(kk + 0) * DDIM + lane], z0);
        z1 = fmaf(scat[w][kk + 1], W[(kk + 1) * DDIM + lane], z1);
        z2 = fmaf(scat[w][kk + 2], W[(kk + 2) * DDIM + lane], z2);
        z3 = fmaf(scat[w][kk + 3], W[(kk + 3) * DDIM + lane], z3);
    }
    float z = (z0 + z1) + (z2 + z3);
    z = fmaxf(z, 0.0f);

    float s2 = z * z;
#pragma unroll
    for (int off = 32; off >= 1; off >>= 1) s2 += __shfl_xor(s2, off);
    const float inv = 1.0f / fmaxf(sqrtf(s2), 1e-12f);
    out[(size_t)row * DDIM + lane] = z * inv;
}

// ---------------------------------------------------------------------------
extern "C" void kernel_launch(void* const* d_in, const int* in_sizes, int n_in,
                              void* d_out, int out_size, void* d_ws, size_t ws_size,
                              hipStream_t stream) {
    const float* X   = (const float*)d_in[0];
    const float* adj = (const float*)d_in[1];
    const float* W   = (const float*)d_in[2];
    const float* b   = (const float*)d_in[3];
    float* out = (float*)d_out;

    const size_t need = (size_t)NROWS * sizeof(int)            // cnt
                      + (size_t)NROWS * MAXN * sizeof(int);    // lists (8 MB)
    if (d_ws != nullptr && ws_size >= need) {
        int* cnt  = (int*)d_ws;
        int* list = cnt + NROWS;
        hipMemsetAsync(cnt, 0, (size_t)NROWS * sizeof(int), stream);
        adj_scan<<<SCAN_BLOCKS, SCAN_TPB, 0, stream>>>(adj, cnt, list);
        sage_agg<<<NBLOCKS, 256, 0, stream>>>(X, cnt, list, W, b, out);
    } else {
        sage_fused<<<NBLOCKS, 256, 0, stream>>>(X, adj, W, b, out);
    }
}

// Round 2
// 1328.361 us; speedup vs baseline: 1.0251x; 1.0251x over previous
//
#include <hip/hip_runtime.h>
#include <stdint.h>

// GraphSAGE fused layer, MI355X (gfx950). All tensors fp32.
// N=16384, D=64. adj = binary fp32 mask (1.074 GB) -> stream once, floor ~170us.
//
// R6 theory: R4 (per-row streams, staggered) and R5 (fill-isomorphic contiguous
// scan) BOTH read adj at ~3.4 TB/s, while the harness's fillBufferAligned
// writes 6.2 TB/s on the same buffer sizes. Pattern theories are dead. The one
// constant across all ~3.4 TB/s readers: __builtin_nontemporal_load on every
// adj access. Hypothesis: nt-flagged reads lose TCC-side coalescing/streaming
// and cap request rate at ~half. Experiment: R4 structure verbatim, nt loads
// replaced with plain cached loads. Single variable vs the 1292 us baseline.
// Risk: adj now allocates in L2 and may evict X (4 MB, re-read ~32x) ->
// bounded +20 us; NT win, if real, is ~-135 us.
//
// One wave per row: 4096 blocks x 4 waves = 16384 waves. No __syncthreads.

#define NROWS   16384
#define DDIM    64
#define MAXNNZ  256       // deg ~ Binom(16384, 32/16384): mean 32, sigma 5.7
#define NBLOCKS 4096

typedef uint32_t u32x4 __attribute__((ext_vector_type(4)));

__global__ __launch_bounds__(256, 4) void sage_fused(
    const float* __restrict__ X,     // (N, 64)
    const float* __restrict__ adj,   // (N, N)
    const float* __restrict__ W,     // (128, 64) row-major, L2-hot (32 KB)
    const float* __restrict__ bias,  // (64,)
    float* __restrict__ out)         // (N, 64)
{
    __shared__ int   slist[4][MAXNNZ];   // per-wave nonzero column list
    __shared__ int   scnt[4];
    __shared__ float scat[4][2 * DDIM];  // per-wave [x_i | h_neigh]

    const int tid  = threadIdx.x;
    const int lane = tid & 63;
    const int w    = tid >> 6;
    const int row  = blockIdx.x * 4 + w;     // one wave per row

    const float bv = bias[lane];

    if (lane == 0) scnt[w] = 0;
    __builtin_amdgcn_wave_barrier();

    // ---- Scan the 64 KB adj row: 16 stages x (4 x 16B/lane), depth-2 pipeline.
    // Staggered start stage breaks cross-wave lockstep on the 64-KB stride.
    const int start = (row * 7 + (row >> 4)) & 15;
    const u32x4* rowp = reinterpret_cast<const u32x4*>(adj + (size_t)row * NROWS);

    u32x4 buf[2][4];
    {
        const int ss0 = start;                 // stage 0
        const int ss1 = (start + 1) & 15;      // stage 1
#pragma unroll
        for (int q = 0; q < 4; ++q)
            buf[0][q] = rowp[ss0 * 256 + q * 64 + lane];   // plain cached load
#pragma unroll
        for (int q = 0; q < 4; ++q)
            buf[1][q] = rowp[ss1 * 256 + q * 64 + lane];
    }

#pragma unroll 2
    for (int s = 0; s < 16; ++s) {
        const int cur = s & 1;
        const int ss  = (s + start) & 15;      // stage being processed
        // Process current stage (compiler can wait vmcnt(4): other buf in flight).
#pragma unroll
        for (int q = 0; q < 4; ++q) {
            const u32x4 vv = buf[cur][q];
            if (vv.x | vv.y | vv.z | vv.w) {          // fp32 0.0f == all-zero bits
                const int base = (ss * 256 + q * 64 + lane) * 4;
                const uint32_t w4[4] = { vv.x, vv.y, vv.z, vv.w };
#pragma unroll
                for (int j = 0; j < 4; ++j) {
                    if (w4[j]) {
                        const int p = atomicAdd(&scnt[w], 1);
                        if (p < MAXNNZ) slist[w][p] = base + j;
                    }
                }
            }
        }
        // Refill this buffer with stage s+2.
        if (s < 14) {
            const int ssn = (s + 2 + start) & 15;
#pragma unroll
            for (int q = 0; q < 4; ++q)
                buf[cur][q] = rowp[ssn * 256 + q * 64 + lane];  // plain cached load
        }
    }
    __builtin_amdgcn_wave_barrier();

    const int nnz = scnt[w];               // DS ops in-order within the wave
    const int cn  = (nnz < MAXNNZ) ? nnz : MAXNNZ;

    // ---- Gather-accumulate neighbor X rows (256 B coalesced reads, cache-hot).
    float acc = 0.0f;
    int k = 0;
    for (; k + 4 <= cn; k += 4) {
        const int j0 = slist[w][k], j1 = slist[w][k + 1];
        const int j2 = slist[w][k + 2], j3 = slist[w][k + 3];
        const float a0 = X[(size_t)j0 * DDIM + lane];
        const float a1 = X[(size_t)j1 * DDIM + lane];
        const float a2 = X[(size_t)j2 * DDIM + lane];
        const float a3 = X[(size_t)j3 * DDIM + lane];
        acc += (a0 + a1) + (a2 + a3);
    }
    for (; k < cn; ++k) acc += X[(size_t)slist[w][k] * DDIM + lane];

    const float xi = X[(size_t)row * DDIM + lane];
    const float h  = (acc + xi) / ((float)nnz + 1.0f);   // deg = rowsum+1 >= 1
    scat[w][lane]        = xi;
    scat[w][DDIM + lane] = h;
    __builtin_amdgcn_wave_barrier();

    // ---- GEMV: z[d] = b[d] + sum_k cat[k] * W[k][d]; W is L1/L2-hot.
    float z0 = bv, z1 = 0.0f, z2 = 0.0f, z3 = 0.0f;
#pragma unroll 8
    for (int kk = 0; kk < 2 * DDIM; kk += 4) {
        z0 = fmaf(scat[w][kk + 0], W[(kk + 0) * DDIM + lane], z0);
        z1 = fmaf(scat[w][kk + 1], W[(kk + 1) * DDIM + lane], z1);
        z2 = fmaf(scat[w][kk + 2], W[(kk + 2) * DDIM + lane], z2);
        z3 = fmaf(scat[w][kk + 3], W[(kk + 3) * DDIM + lane], z3);
    }
    float z = (z0 + z1) + (z2 + z3);
    z = fmaxf(z, 0.0f);

    // ---- Row L2-norm over the 64 lanes, normalize, store.
    float s2 = z * z;
#pragma unroll
    for (int off = 32; off >= 1; off >>= 1) s2 += __shfl_xor(s2, off);
    const float inv = 1.0f / fmaxf(sqrtf(s2), 1e-12f);
    out[(size_t)row * DDIM + lane] = z * inv;
}

extern "C" void kernel_launch(void* const* d_in, const int* in_sizes, int n_in,
                              void* d_out, int out_size, void* d_ws, size_t ws_size,
                              hipStream_t stream) {
    const float* X   = (const float*)d_in[0];
    const float* adj = (const float*)d_in[1];
    const float* W   = (const float*)d_in[2];
    const float* b   = (const float*)d_in[3];
    float* out = (float*)d_out;
    sage_fused<<<NBLOCKS, 256, 0, stream>>>(X, adj, W, b, out);
}

// Round 3
// 1316.677 us; speedup vs baseline: 1.0342x; 1.0089x over previous
//
#include <hip/hip_runtime.h>
#include <stdint.h>

// GraphSAGE fused layer, MI355X (gfx950). All tensors fp32.
// N=16384, D=64. adj = binary fp32 mask (1.074 GB) -> stream once.
//
// R7: R6 showed cached adj loads are ~55us WORSE (L2 pollution evicts X) ->
// NT restored. All read designs so far (per-row NT, contiguous NT, per-row
// cached) hit ~3.4 TB/s at 16 waves/CU, vs 6.3 TB/s pure-write fill. Little's
// law says effective in-flight is only ~5 KB/CU -> suspect per-CU TCP/MSHR
// queue occupancy, not HBM, is the clamp. Single variable this round:
// __launch_bounds__(256, 8) -> 32 waves/CU (2x queue pressure). If unchanged,
// ~3.4 TB/s is the chip's pure-read wall and we are at the roofline.
//
// One wave per row: 4096 blocks x 4 waves = 16384 waves. No __syncthreads.

#define NROWS   16384
#define DDIM    64
#define MAXNNZ  256       // deg ~ Binom(16384, 32/16384): mean 32, sigma 5.7
#define NBLOCKS 4096

typedef uint32_t u32x4 __attribute__((ext_vector_type(4)));

__global__ __launch_bounds__(256, 8) void sage_fused(
    const float* __restrict__ X,     // (N, 64)
    const float* __restrict__ adj,   // (N, N)
    const float* __restrict__ W,     // (128, 64) row-major, L2-hot (32 KB)
    const float* __restrict__ bias,  // (64,)
    float* __restrict__ out)         // (N, 64)
{
    __shared__ int   slist[4][MAXNNZ];   // per-wave nonzero column list
    __shared__ int   scnt[4];
    __shared__ float scat[4][2 * DDIM];  // per-wave [x_i | h_neigh]

    const int tid  = threadIdx.x;
    const int lane = tid & 63;
    const int w    = tid >> 6;
    const int row  = blockIdx.x * 4 + w;     // one wave per row

    const float bv = bias[lane];

    if (lane == 0) scnt[w] = 0;
    __builtin_amdgcn_wave_barrier();

    // ---- Scan the 64 KB adj row: 16 stages x (4 x 16B/lane), depth-2 pipeline.
    // Staggered start stage breaks cross-wave lockstep on the 64-KB stride.
    const int start = (row * 7 + (row >> 4)) & 15;
    const u32x4* rowp = reinterpret_cast<const u32x4*>(adj + (size_t)row * NROWS);

    u32x4 buf[2][4];
    {
        const int ss0 = start;                 // stage 0
        const int ss1 = (start + 1) & 15;      // stage 1
#pragma unroll
        for (int q = 0; q < 4; ++q)
            buf[0][q] = __builtin_nontemporal_load(&rowp[ss0 * 256 + q * 64 + lane]);
#pragma unroll
        for (int q = 0; q < 4; ++q)
            buf[1][q] = __builtin_nontemporal_load(&rowp[ss1 * 256 + q * 64 + lane]);
    }

#pragma unroll 2
    for (int s = 0; s < 16; ++s) {
        const int cur = s & 1;
        const int ss  = (s + start) & 15;      // stage being processed
        // Process current stage (compiler can wait vmcnt(4): other buf in flight).
#pragma unroll
        for (int q = 0; q < 4; ++q) {
            const u32x4 vv = buf[cur][q];
            if (vv.x | vv.y | vv.z | vv.w) {          // fp32 0.0f == all-zero bits
                const int base = (ss * 256 + q * 64 + lane) * 4;
                const uint32_t w4[4] = { vv.x, vv.y, vv.z, vv.w };
#pragma unroll
                for (int j = 0; j < 4; ++j) {
                    if (w4[j]) {
                        const int p = atomicAdd(&scnt[w], 1);
                        if (p < MAXNNZ) slist[w][p] = base + j;
                    }
                }
            }
        }
        // Refill this buffer with stage s+2.
        if (s < 14) {
            const int ssn = (s + 2 + start) & 15;
#pragma unroll
            for (int q = 0; q < 4; ++q)
                buf[cur][q] = __builtin_nontemporal_load(&rowp[ssn * 256 + q * 64 + lane]);
        }
    }
    __builtin_amdgcn_wave_barrier();

    const int nnz = scnt[w];               // DS ops in-order within the wave
    const int cn  = (nnz < MAXNNZ) ? nnz : MAXNNZ;

    // ---- Gather-accumulate neighbor X rows (256 B coalesced reads, cache-hot).
    float acc = 0.0f;
    int k = 0;
    for (; k + 4 <= cn; k += 4) {
        const int j0 = slist[w][k], j1 = slist[w][k + 1];
        const int j2 = slist[w][k + 2], j3 = slist[w][k + 3];
        const float a0 = X[(size_t)j0 * DDIM + lane];
        const float a1 = X[(size_t)j1 * DDIM + lane];
        const float a2 = X[(size_t)j2 * DDIM + lane];
        const float a3 = X[(size_t)j3 * DDIM + lane];
        acc += (a0 + a1) + (a2 + a3);
    }
    for (; k < cn; ++k) acc += X[(size_t)slist[w][k] * DDIM + lane];

    const float xi = X[(size_t)row * DDIM + lane];
    const float h  = (acc + xi) / ((float)nnz + 1.0f);   // deg = rowsum+1 >= 1
    scat[w][lane]        = xi;
    scat[w][DDIM + lane] = h;
    __builtin_amdgcn_wave_barrier();

    // ---- GEMV: z[d] = b[d] + sum_k cat[k] * W[k][d]; W is L1/L2-hot.
    float z0 = bv, z1 = 0.0f, z2 = 0.0f, z3 = 0.0f;
#pragma unroll 8
    for (int kk = 0; kk < 2 * DDIM; kk += 4) {
        z0 = fmaf(scat[w][kk + 0], W[(kk + 0) * DDIM + lane], z0);
        z1 = fmaf(scat[w][kk + 1], W[(kk + 1) * DDIM + lane], z1);
        z2 = fmaf(scat[w][kk + 2], W[(kk + 2) * DDIM + lane], z2);
        z3 = fmaf(scat[w][kk + 3], W[(kk + 3) * DDIM + lane], z3);
    }
    float z = (z0 + z1) + (z2 + z3);
    z = fmaxf(z, 0.0f);

    // ---- Row L2-norm over the 64 lanes, normalize, store.
    float s2 = z * z;
#pragma unroll
    for (int off = 32; off >= 1; off >>= 1) s2 += __shfl_xor(s2, off);
    const float inv = 1.0f / fmaxf(sqrtf(s2), 1e-12f);
    out[(size_t)row * DDIM + lane] = z * inv;
}

extern "C" void kernel_launch(void* const* d_in, const int* in_sizes, int n_in,
                              void* d_out, int out_size, void* d_ws, size_t ws_size,
                              hipStream_t stream) {
    const float* X   = (const float*)d_in[0];
    const float* adj = (const float*)d_in[1];
    const float* W   = (const float*)d_in[2];
    const float* b   = (const float*)d_in[3];
    float* out = (float*)d_out;
    sage_fused<<<NBLOCKS, 256, 0, stream>>>(X, adj, W, b, out);
}

// Round 4
// 1290.581 us; speedup vs baseline: 1.0551x; 1.0202x over previous
//
#include <hip/hip_runtime.h>
#include <stdint.h>

// GraphSAGE fused layer, MI355X (gfx950). All tensors fp32.
// N=16384, D=64. adj = binary fp32 mask (1.074 GB) -> stream once.
//
// R8: read-wall post-mortems: pattern (R5), NT (R6), occupancy (R7) all
// refuted; adj reads stuck at ~3.4 TB/s while pure-write fill does 6.4.
// Remaining common factor: divergent CF + LDS atomicAdd between load issues.
// MISched can't hoist global loads across divergent branches -> each wave's
// issue stream has a few-hundred-cycle bubble per 4 KB stage. This round:
// branchless scan. Per 16B vec: 4x {__ballot(nz) -> mbcnt rank -> predicated
// ds_write}, wave-uniform count in a register (no atomics, no branches).
// Buffers consumed into temps first so refill loads issue BEFORE processing.
// Everything else identical to the 1292us baseline (NT, 16 waves/CU, tail).
//
// One wave per row: 4096 blocks x 4 waves = 16384 waves. No __syncthreads.

#define NROWS   16384
#define DDIM    64
#define MAXNNZ  256       // deg ~ Binom(16384, 32/16384): mean 32, sigma 5.7
#define NBLOCKS 4096

typedef uint32_t u32x4 __attribute__((ext_vector_type(4)));

__device__ __forceinline__ int lane_rank(unsigned long long m) {
    // count of set bits among lanes strictly below this lane
    return __builtin_amdgcn_mbcnt_hi((uint32_t)(m >> 32),
           __builtin_amdgcn_mbcnt_lo((uint32_t)m, 0));
}

__global__ __launch_bounds__(256, 4) void sage_fused(
    const float* __restrict__ X,     // (N, 64)
    const float* __restrict__ adj,   // (N, N)
    const float* __restrict__ W,     // (128, 64) row-major, L2-hot (32 KB)
    const float* __restrict__ bias,  // (64,)
    float* __restrict__ out)         // (N, 64)
{
    __shared__ int   slist[4][MAXNNZ];   // per-wave nonzero column list
    __shared__ float scat[4][2 * DDIM];  // per-wave [x_i | h_neigh]

    const int tid  = threadIdx.x;
    const int lane = tid & 63;
    const int w    = tid >> 6;
    const int row  = blockIdx.x * 4 + w;     // one wave per row

    const float bv = bias[lane];

    // ---- Scan the 64 KB adj row: 16 stages x (4 x 16B/lane), depth-2 pipeline.
    const int start = (row * 7 + (row >> 4)) & 15;
    const u32x4* rowp = reinterpret_cast<const u32x4*>(adj + (size_t)row * NROWS);

    u32x4 buf[2][4];
    {
        const int ss0 = start;                 // stage 0
        const int ss1 = (start + 1) & 15;      // stage 1
#pragma unroll
        for (int q = 0; q < 4; ++q)
            buf[0][q] = __builtin_nontemporal_load(&rowp[ss0 * 256 + q * 64 + lane]);
#pragma unroll
        for (int q = 0; q < 4; ++q)
            buf[1][q] = __builtin_nontemporal_load(&rowp[ss1 * 256 + q * 64 + lane]);
    }

    int cnt = 0;   // wave-uniform running nonzero count (same in all lanes)

#pragma unroll 2
    for (int s = 0; s < 16; ++s) {
        const int cur = s & 1;
        const int ss  = (s + start) & 15;      // stage being processed

        // Consume buffer registers into temps (vmcnt wait happens here)...
        u32x4 t[4];
#pragma unroll
        for (int q = 0; q < 4; ++q) t[q] = buf[cur][q];

        // ...so the refill loads can issue BEFORE the processing VALU work.
        if (s < 14) {
            const int ssn = (s + 2 + start) & 15;
#pragma unroll
            for (int q = 0; q < 4; ++q)
                buf[cur][q] = __builtin_nontemporal_load(&rowp[ssn * 256 + q * 64 + lane]);
        }

        // Branchless nonzero extraction: ballot + mbcnt rank + predicated write.
#pragma unroll
        for (int q = 0; q < 4; ++q) {
            const u32x4 vv = t[q];
            const int base = (ss * 256 + q * 64 + lane) * 4;
            const uint32_t w4[4] = { vv.x, vv.y, vv.z, vv.w };
#pragma unroll
            for (int j = 0; j < 4; ++j) {
                const bool nz = (w4[j] != 0);
                const unsigned long long m = __ballot(nz);
                const int p = cnt + lane_rank(m);
                if (nz && p < MAXNNZ) slist[w][p] = base + j;  // predicated store
                cnt += (int)__popcll(m);                       // uniform update
            }
        }
    }
    __builtin_amdgcn_wave_barrier();

    const int nnz = cnt;
    const int cn  = (nnz < MAXNNZ) ? nnz : MAXNNZ;

    // ---- Gather-accumulate neighbor X rows (256 B coalesced reads, cache-hot).
    float acc = 0.0f;
    int k = 0;
    for (; k + 4 <= cn; k += 4) {
        const int j0 = slist[w][k], j1 = slist[w][k + 1];
        const int j2 = slist[w][k + 2], j3 = slist[w][k + 3];
        const float a0 = X[(size_t)j0 * DDIM + lane];
        const float a1 = X[(size_t)j1 * DDIM + lane];
        const float a2 = X[(size_t)j2 * DDIM + lane];
        const float a3 = X[(size_t)j3 * DDIM + lane];
        acc += (a0 + a1) + (a2 + a3);
    }
    for (; k < cn; ++k) acc += X[(size_t)slist[w][k] * DDIM + lane];

    const float xi = X[(size_t)row * DDIM + lane];
    const float h  = (acc + xi) / ((float)nnz + 1.0f);   // deg = rowsum+1 >= 1
    scat[w][lane]        = xi;
    scat[w][DDIM + lane] = h;
    __builtin_amdgcn_wave_barrier();

    // ---- GEMV: z[d] = b[d] + sum_k cat[k] * W[k][d]; W is L1/L2-hot.
    float z0 = bv, z1 = 0.0f, z2 = 0.0f, z3 = 0.0f;
#pragma unroll 8
    for (int kk = 0; kk < 2 * DDIM; kk += 4) {
        z0 = fmaf(scat[w][kk + 0], W[(kk + 0) * DDIM + lane], z0);
        z1 = fmaf(scat[w][kk + 1], W[(kk + 1) * DDIM + lane], z1);
        z2 = fmaf(scat[w][kk + 2], W[(kk + 2) * DDIM + lane], z2);
        z3 = fmaf(scat[w][kk + 3], W[(kk + 3) * DDIM + lane], z3);
    }
    float z = (z0 + z1) + (z2 + z3);
    z = fmaxf(z, 0.0f);

    // ---- Row L2-norm over the 64 lanes, normalize, store.
    float s2 = z * z;
#pragma unroll
    for (int off = 32; off >= 1; off >>= 1) s2 += __shfl_xor(s2, off);
    const float inv = 1.0f / fmaxf(sqrtf(s2), 1e-12f);
    out[(size_t)row * DDIM + lane] = z * inv;
}

extern "C" void kernel_launch(void* const* d_in, const int* in_sizes, int n_in,
                              void* d_out, int out_size, void* d_ws, size_t ws_size,
                              hipStream_t stream) {
    const float* X   = (const float*)d_in[0];
    const float* adj = (const float*)d_in[1];
    const float* W   = (const float*)d_in[2];
    const float* b   = (const float*)d_in[3];
    float* out = (float*)d_out;
    sage_fused<<<NBLOCKS, 256, 0, stream>>>(X, adj, W, b, out);
}